// Round 4
// baseline (244.990 us; speedup 1.0000x reference)
//
#include <hip/hip_runtime.h>
#include <math.h>
#include <stdint.h>

#define B 4
#define S 4096
#define E 768
#define H 64
#define NMAT 192   // 3*64 output columns (q|k|v)

typedef _Float16 half_t;
typedef __attribute__((ext_vector_type(8))) _Float16 half8;
typedef __attribute__((ext_vector_type(4))) _Float16 half4;
typedef __attribute__((ext_vector_type(4))) float f32x4;
typedef __attribute__((ext_vector_type(16))) float f32x16;
typedef __attribute__((ext_vector_type(4))) unsigned int uint4v;

#define LOG2E 1.4426950408889634f

// ---------------- W prep: fp16 Dekker split ----------------
// Wst layout: [kstep 24][n 192][part 2][32]  (n = mat*64+h, part 0=hi 1=lo)
__global__ __launch_bounds__(256) void wprep_kernel(
    const float* __restrict__ Wq, const float* __restrict__ Wk,
    const float* __restrict__ Wv, half_t* __restrict__ Wst)
{
    int gid = blockIdx.x * 256 + threadIdx.x;     // 0..147455
    int m = gid / (H * E);
    int rem = gid - m * (H * E);
    int h = rem / E;
    int e = rem - h * E;
    const float* W = (m == 0) ? Wq : (m == 1) ? Wk : Wv;
    float val = W[h * E + e];
    half_t hi = (half_t)val;
    float lo = val - (float)hi;
    int n = m * H + h;
    int ks = e >> 5, kk = e & 31;
    size_t base = ((size_t)(ks * NMAT + n) * 2) * 32 + kk;
    Wst[base]      = hi;
    Wst[base + 32] = (half_t)lo;
}

// ---------------- Projection v3: zero-LDS, register-pipelined ----------------
// grid 512 x 512 thr (8 waves = msub 2 x nsplit 4), 32 M-rows/block.
// Round-3 lesson: without LDS the compiler issues loads in-iteration (VGPR=32,
// MfmaUtil 5%) -> serial load->MFMA chain. Fix: manual unroll-2 with explicit
// A/B register sets so kstep k+1's x and W fragments are IN FLIGHT during
// kstep k's MFMAs. W (576 KB) is L2-resident / L1-hot; x is the HBM stream.
// No barriers, no LDS; 4 waves/SIMD.
// q is scaled by 1/8 (exact pow2) so flash's scores come out as qk/8.
__global__ __launch_bounds__(512, 4) void proj_kernel(
    const float* __restrict__ x, const half_t* __restrict__ Wst,
    half_t* __restrict__ qhi, half_t* __restrict__ qlo,
    half_t* __restrict__ khi, half_t* __restrict__ klo,
    half_t* __restrict__ vt)
{
    const int t = threadIdx.x;
    const int w = t >> 6, lane = t & 63;
    const int col = lane & 15, quad = lane >> 4;
    const int nsplit = w & 3, msub = w >> 2;
    const int mrow = blockIdx.x * 32 + msub * 16 + col;

    f32x4 aqh = {0.f,0.f,0.f,0.f}, aqm = {0.f,0.f,0.f,0.f};
    f32x4 akh = {0.f,0.f,0.f,0.f}, akm = {0.f,0.f,0.f,0.f};
    f32x4 av  = {0.f,0.f,0.f,0.f};

    const float* xrow = x + (size_t)mrow * E + quad * 8;
    const int nq = nsplit * 16 + col;                 // q row 0..63
    const size_t wqo = (size_t)nq * 64 + quad * 8;    // within a kstep slab
    const size_t wko = wqo + (size_t)64 * 64;         // k rows at +64
    const size_t wvo = wqo + (size_t)128 * 64;        // v rows at +128

    auto pload = [&](int ks, float4& xa, float4& xb, half8& bhq, half8& blq,
                     half8& bhk, half8& blk, half8& bhv) {
        const float* xp = xrow + ks * 32;
        xa = *(const float4*)xp;
        xb = *(const float4*)(xp + 4);
        const half_t* wb = Wst + (size_t)ks * (NMAT * 64);
        bhq = *(const half8*)(wb + wqo);
        blq = *(const half8*)(wb + wqo + 32);
        bhk = *(const half8*)(wb + wko);
        blk = *(const half8*)(wb + wko + 32);
        bhv = *(const half8*)(wb + wvo);
    };
    auto pcomp = [&](const float4& xa, const float4& xb, const half8& bhq,
                     const half8& blq, const half8& bhk, const half8& blk,
                     const half8& bhv) {
        float xv[8] = {xa.x, xa.y, xa.z, xa.w, xb.x, xb.y, xb.z, xb.w};
        half8 ah, al;
        #pragma unroll
        for (int j = 0; j < 8; ++j) {
            half_t hi = (half_t)xv[j];
            ah[j] = hi;
            al[j] = (half_t)(xv[j] - (float)hi);
        }
        aqh = __builtin_amdgcn_mfma_f32_16x16x32_f16(ah, bhq, aqh, 0, 0, 0);
        aqm = __builtin_amdgcn_mfma_f32_16x16x32_f16(al, bhq, aqm, 0, 0, 0);
        aqm = __builtin_amdgcn_mfma_f32_16x16x32_f16(ah, blq, aqm, 0, 0, 0);
        akh = __builtin_amdgcn_mfma_f32_16x16x32_f16(ah, bhk, akh, 0, 0, 0);
        akm = __builtin_amdgcn_mfma_f32_16x16x32_f16(al, bhk, akm, 0, 0, 0);
        akm = __builtin_amdgcn_mfma_f32_16x16x32_f16(ah, blk, akm, 0, 0, 0);
        av  = __builtin_amdgcn_mfma_f32_16x16x32_f16(ah, bhv, av,  0, 0, 0);
    };

    float4 xa0, xb0, xa1, xb1;
    half8 bhq0, blq0, bhk0, blk0, bhv0;
    half8 bhq1, blq1, bhk1, blk1, bhv1;

    pload(0, xa0, xb0, bhq0, blq0, bhk0, blk0, bhv0);
    for (int ks = 0; ks < 24; ks += 2) {
        pload(ks + 1, xa1, xb1, bhq1, blq1, bhk1, blk1, bhv1);
        pcomp(xa0, xb0, bhq0, blq0, bhk0, blk0, bhv0);
        if (ks + 2 < 24)
            pload(ks + 2, xa0, xb0, bhq0, blq0, bhk0, blk0, bhv0);
        pcomp(xa1, xb1, bhq1, blq1, bhk1, blk1, bhv1);
    }

    // Epilogue. C-layout (16x16): row = quad*4+r, col = lane&15.
    const int srow0 = blockIdx.x * 32 + msub * 16 + quad * 4;
    const int hcol = nsplit * 16 + col;
    #pragma unroll
    for (int r = 0; r < 4; ++r) {
        int srow = srow0 + r;
        float vq = (aqh[r] + aqm[r]) * 0.125f;   // fold 1/sqrt(H) into q
        half_t hq = (half_t)vq;
        qhi[(size_t)srow * H + hcol] = hq;
        qlo[(size_t)srow * H + hcol] = (half_t)(vq - (float)hq);
        float vk = akh[r] + akm[r];
        half_t hk = (half_t)vk;
        khi[(size_t)srow * H + hcol] = hk;
        klo[(size_t)srow * H + hcol] = (half_t)(vk - (float)hk);
    }
    {   // v transposed [b][dim][S]
        half4 pk;
        #pragma unroll
        for (int r = 0; r < 4; ++r) pk[r] = (half_t)av[r];
        int bb = srow0 >> 12, s0 = srow0 & (S - 1);
        *(half4*)(vt + ((size_t)(bb * H + hcol)) * S + s0) = pk;
    }
}

// ---------------- Flash attention v5: zero-LDS, register-pipelined ----------------
// grid 512 x 256 thr. Block: 32 q-rows, 4 waves = 4 key-slices of each
// 128-key tile, 32 tiles. NO LDS and NO barriers in the main loop:
//  - K hi/lo fragments load DIRECTLY from global (L2-resident; swapped-QK
//    A-layout is 16B-contiguous per lane, same shape as the V loads) and are
//    double-buffered in registers one tile ahead;
//  - V fragments load at iteration top, covered by QK^T + softmax;
//  - with no barriers, the compiler's counted s_waitcnt vmcnt(N) pipelining
//    keeps the next tile's 8 K-loads in flight across the whole body.
// Swapped QK^T keeps P in registers (cvt_pkrtz + permlane32_swap).
// LDS (35 KB) only for the 4-way key-slice combine in the epilogue.
__global__ __launch_bounds__(256, 2) void flash_kernel(
    const half_t* __restrict__ qhi, const half_t* __restrict__ qlo,
    const half_t* __restrict__ khi, const half_t* __restrict__ klo,
    const half_t* __restrict__ vt, float* __restrict__ out)
{
    __shared__ __align__(16) char smem[35328];   // Oc 34816 + l_s 512 (epilogue only)

    const int t = threadIdx.x;
    const int w = t >> 6, lane = t & 63;          // w = key-slice 0..3
    const int n32 = lane & 31, l5 = lane >> 5;

    // XCD-aware swizzle: XCD pair {2b,2b+1} serves batch b (K/V fit its L2s)
    const int bid = blockIdx.x;
    const int b = (bid & 7) >> 1;
    const int qt = ((bid >> 3) << 1) | (bid & 1); // 0..127
    const int qrow0 = b * S + qt * 32;

    const half_t* kh_g = khi + (size_t)b * S * H;
    const half_t* kl_g = klo + (size_t)b * S * H;
    const half_t* vt_g = vt + (size_t)b * H * S;

    // Q as MFMA B-fragment: n = q-row = lane&31, k = l5*8+j  (4 k-steps, hi/lo)
    half8 qh[4], ql[4];
    #pragma unroll
    for (int ks = 0; ks < 4; ++ks) {
        size_t off = (size_t)(qrow0 + n32) * H + ks * 16 + l5 * 8;
        qh[ks] = *(const half8*)(qhi + off);
        ql[ks] = *(const half8*)(qlo + off);
    }

    // per-lane fixed offsets: key row (A-frag) and V row (B-frag)
    const size_t krow_off = (size_t)(w * 32 + n32) * H + l5 * 8;
    const half_t* vrow = vt_g + (size_t)n32 * S + w * 32 + l5 * 8;

    f32x16 Oa, Ob;
    #pragma unroll
    for (int r = 0; r < 16; ++r) { Oa[r] = 0.f; Ob[r] = 0.f; }
    float lacc = 0.f;

    // K fragments for one tile: [0..3]=hi(ks), [4..7]=lo(ks)
    auto loadk = [&](int kt, half8 (&kf)[8]) {
        const half_t* kp = kh_g + krow_off + (size_t)kt * (128 * H);
        const half_t* lp = kl_g + krow_off + (size_t)kt * (128 * H);
        #pragma unroll
        for (int ks = 0; ks < 4; ++ks) {
            kf[ks]     = *(const half8*)(kp + ks * 16);
            kf[4 + ks] = *(const half8*)(lp + ks * 16);
        }
    };
    // V fragments: [0]=ks2 0 dims 0..31, [1]=ks2 1 dims 0..31, [2],[3]=dims 32..63
    auto loadv = [&](int kt, half8 (&vf)[4]) {
        const half_t* vp = vrow + kt * 128;
        vf[0] = *(const half8*)(vp);
        vf[1] = *(const half8*)(vp + 16);
        vf[2] = *(const half8*)(vp + (size_t)32 * S);
        vf[3] = *(const half8*)(vp + (size_t)32 * S + 16);
    };

    auto compute = [&](const half8 (&kf)[8], const half8 (&vf)[4]) {
        // ---- QK^T swapped: acc = K*Q^T, lane n32 = q-row, regs = keys ----
        f32x16 acc, acc2;
        #pragma unroll
        for (int r = 0; r < 16; ++r) { acc[r] = 0.f; acc2[r] = 0.f; }
        __builtin_amdgcn_s_setprio(1);
        #pragma unroll
        for (int ks = 0; ks < 4; ++ks) {
            acc  = __builtin_amdgcn_mfma_f32_32x32x16_f16(kf[ks],     qh[ks], acc,  0, 0, 0);
            acc2 = __builtin_amdgcn_mfma_f32_32x32x16_f16(kf[ks],     ql[ks], acc2, 0, 0, 0);
            acc  = __builtin_amdgcn_mfma_f32_32x32x16_f16(kf[4 + ks], qh[ks], acc,  0, 0, 0);
        }
        __builtin_amdgcn_s_setprio(0);
        #pragma unroll
        for (int r = 0; r < 16; ++r) acc[r] += acc2[r];

        // ---- fixed-max softmax, P stays in registers ----
        // key(r) = (r&3) + 8*(r>>2) + 4*l5  (acc already = qk/8)
        unsigned int h0[4], h1[4];
        #pragma unroll
        for (int m = 0; m < 4; ++m) {
            float p0 = exp2f((floorf(acc[4 * m + 0]) - 8.0f) * LOG2E);
            float p1 = exp2f((floorf(acc[4 * m + 1]) - 8.0f) * LOG2E);
            float p2 = exp2f((floorf(acc[4 * m + 2]) - 8.0f) * LOG2E);
            float p3 = exp2f((floorf(acc[4 * m + 3]) - 8.0f) * LOG2E);
            lacc += p0 + p1 + p2 + p3;
            h0[m] = __builtin_bit_cast(unsigned int, __builtin_amdgcn_cvt_pkrtz(p0, p1));
            h1[m] = __builtin_bit_cast(unsigned int, __builtin_amdgcn_cvt_pkrtz(p2, p3));
        }

        // ---- PV: build A-frags with permlane32_swap, no LDS ----
        __builtin_amdgcn_s_setprio(1);
        #pragma unroll
        for (int ks2 = 0; ks2 < 2; ++ks2) {
            auto s1 = __builtin_amdgcn_permlane32_swap(h0[2 * ks2], h0[2 * ks2 + 1], false, false);
            auto s2 = __builtin_amdgcn_permlane32_swap(h1[2 * ks2], h1[2 * ks2 + 1], false, false);
            uint4v pw;
            pw[0] = s1[0]; pw[1] = s2[0]; pw[2] = s1[1]; pw[3] = s2[1];
            half8 pf = __builtin_bit_cast(half8, pw);
            Oa = __builtin_amdgcn_mfma_f32_32x32x16_f16(pf, vf[ks2], Oa, 0, 0, 0);
            Ob = __builtin_amdgcn_mfma_f32_32x32x16_f16(pf, vf[2 + ks2], Ob, 0, 0, 0);
        }
        __builtin_amdgcn_s_setprio(0);
    };

    half8 ka[8], kb[8], va[4], vb[4];
    loadk(0, ka);
    for (int kt = 0; kt < 32; kt += 2) {
        loadv(kt, va);
        loadk(kt + 1, kb);
        compute(ka, va);
        loadv(kt + 1, vb);
        if (kt + 2 < 32) loadk(kt + 2, ka);
        compute(kb, vb);
    }

    // ---- denominator: other 16 keys live in the opposite lane-half ----
    lacc += __shfl_xor(lacc, 32);

    // ---- combine the 4 key-slice partials via LDS ----
    // Oc [4 ksw][32 rows][68] floats (stride 68 dodges conflicts), l_s [4][32]
    float* Oc  = (float*)smem;
    float* l_s = (float*)(smem + 34816);
    #pragma unroll
    for (int r = 0; r < 16; ++r) {
        int rowl = (r & 3) + 8 * (r >> 2) + 4 * l5;
        Oc[(w * 32 + rowl) * 68 + n32]      = Oa[r];
        Oc[(w * 32 + rowl) * 68 + 32 + n32] = Ob[r];
    }
    if (lane < 32) l_s[w * 32 + n32] = lacc;
    __syncthreads();

    {
        int row = t >> 3;            // 0..31
        int d0 = (t & 7) * 8;        // 0..56
        float den = l_s[row] + l_s[32 + row] + l_s[64 + row] + l_s[96 + row];
        float s0 = 0.f, s1 = 0.f, s2 = 0.f, s3 = 0.f;
        float s4 = 0.f, s5 = 0.f, s6 = 0.f, s7 = 0.f;
        #pragma unroll
        for (int k = 0; k < 4; ++k) {
            const float* oc = Oc + (size_t)(k * 32 + row) * 68 + d0;
            float4 a = *(const float4*)oc;
            float4 bq = *(const float4*)(oc + 4);
            s0 += a.x;  s1 += a.y;  s2 += a.z;  s3 += a.w;
            s4 += bq.x; s5 += bq.y; s6 += bq.z; s7 += bq.w;
        }
        float inv = 1.f / den;
        float4 o1 = make_float4(s0 * inv, s1 * inv, s2 * inv, s3 * inv);
        float4 o2 = make_float4(s4 * inv, s5 * inv, s6 * inv, s7 * inv);
        float* op = out + (size_t)(qrow0 + row) * H + d0;
        *(float4*)op = o1;
        *(float4*)(op + 4) = o2;
    }
}

extern "C" void kernel_launch(void* const* d_in, const int* in_sizes, int n_in,
                              void* d_out, int out_size, void* d_ws, size_t ws_size,
                              hipStream_t stream) {
    const float* x  = (const float*)d_in[0];
    const float* Wq = (const float*)d_in[1];
    const float* Wk = (const float*)d_in[2];
    const float* Wv = (const float*)d_in[3];
    float* outp = (float*)d_out;

    const size_t N = (size_t)B * S * H;          // 1,048,576
    half_t* qhi = (half_t*)d_ws;
    half_t* qlo = qhi + N;
    half_t* khi = qlo + N;
    half_t* klo = khi + N;
    half_t* vt  = klo + N;
    half_t* Wst = vt + N;                        // 294912 halves

    wprep_kernel<<<(3 * H * E) / 256, 256, 0, stream>>>(Wq, Wk, Wv, Wst);
    proj_kernel<<<(B * S) / 32, 512, 0, stream>>>(x, Wst, qhi, qlo, khi, klo, vt);
    flash_kernel<<<B * (S / 32), 256, 0, stream>>>(qhi, qlo, khi, klo, vt, outp);
}

// Round 5
// 223.394 us; speedup vs baseline: 1.0967x; 1.0967x over previous
//
#include <hip/hip_runtime.h>
#include <math.h>
#include <stdint.h>

#define B 4
#define S 4096
#define E 768
#define H 64
#define NMAT 192   // 3*64 output columns (q|k|v)

typedef _Float16 half_t;
typedef __attribute__((ext_vector_type(8))) _Float16 half8;
typedef __attribute__((ext_vector_type(4))) _Float16 half4;
typedef __attribute__((ext_vector_type(4))) float f32x4;
typedef __attribute__((ext_vector_type(16))) float f32x16;
typedef __attribute__((ext_vector_type(4))) unsigned int uint4v;

#define LOG2E 1.4426950408889634f

__device__ __forceinline__ void gload_lds16(const void* g, void* l) {
    __builtin_amdgcn_global_load_lds(
        (const __attribute__((address_space(1))) unsigned int*)g,
        (__attribute__((address_space(3))) unsigned int*)l, 16, 0, 0);
}

// ---------------- W prep: fp16 Dekker split, chunk-swizzled ----------------
// Wst layout: [kstep 24][n 192][8 chunks of 8 halves].
// Logical chunk j: 0..3 = hi[kk 0..31], 4..7 = lo[kk 0..31]; stored at
// physical chunk p = j ^ (n&7) so proj's linear global_load_lds image gives
// bank-spread fragment reads (same scheme as flash's K staging).
__global__ __launch_bounds__(256) void wprep_kernel(
    const float* __restrict__ Wq, const float* __restrict__ Wk,
    const float* __restrict__ Wv, half_t* __restrict__ Wst)
{
    int gid = blockIdx.x * 256 + threadIdx.x;     // 0..147455
    int m = gid / (H * E);
    int rem = gid - m * (H * E);
    int h = rem / E;
    int e = rem - h * E;
    const float* W = (m == 0) ? Wq : (m == 1) ? Wk : Wv;
    float val = W[h * E + e];
    half_t hi = (half_t)val;
    float lo = val - (float)hi;
    int n = m * H + h;
    int ks = e >> 5, kk = e & 31;
    int jh = kk >> 3, pos = kk & 7, sw = n & 7;
    size_t base = ((size_t)(ks * NMAT + n)) * 64;
    Wst[base + ((jh ^ sw) << 3) + pos]       = hi;
    Wst[base + (((jh + 4) ^ sw) << 3) + pos] = (half_t)lo;
}

// ---------------- Projection v4: DMA-staged, counted-vmcnt pipeline ----------------
// grid 512 x 512 thr (8 waves = msub 2 x nsplit 4), 32 M-rows/block.
// Per kstep: 24 KB W slab staged via global_load_lds (3 x 16B per thread),
// double-buffered. NO __syncthreads (its vmcnt(0) drain was the stall):
// per kstep  [stage ks+1][x-load ks+1][vmcnt(5)][s_barrier][compute ks]
//            [lgkmcnt(0)][s_barrier]
// vmcnt(5) leaves this iteration's 3 DMAs + 2 x-loads in flight and forces
// everything older (the tile being computed) -- reorder-proof since prev-iter
// ops are strictly older. LDS 48 KB -> 2 blocks/CU = 16 waves/CU.
// q is scaled by 1/8 (exact pow2) so flash's scores come out as qk/8.
__global__ __launch_bounds__(512, 4) void proj_kernel(
    const float* __restrict__ x, const half_t* __restrict__ Wst,
    half_t* __restrict__ qhi, half_t* __restrict__ qlo,
    half_t* __restrict__ khi, half_t* __restrict__ klo,
    half_t* __restrict__ vt)
{
    __shared__ __align__(16) half_t W_s[2][NMAT * 64];   // 2 x 24576 B

    const int t = threadIdx.x;
    const int w = t >> 6, lane = t & 63;
    const int col = lane & 15, quad = lane >> 4;
    const int nsplit = w & 3, msub = w >> 2;
    const int mrow = blockIdx.x * 32 + msub * 16 + col;

    f32x4 aqh = {0.f,0.f,0.f,0.f}, aqm = {0.f,0.f,0.f,0.f};
    f32x4 akh = {0.f,0.f,0.f,0.f}, akm = {0.f,0.f,0.f,0.f};
    f32x4 av  = {0.f,0.f,0.f,0.f};

    const float* xrow = x + (size_t)mrow * E + quad * 8;
    const int nq = nsplit * 16 + col;                     // q row 0..63
    const int oh = (quad ^ (col & 7)) << 3;               // hi chunk offset
    const int ol = ((quad + 4) ^ (col & 7)) << 3;         // lo chunk offset

    auto stage = [&](int ks, half_t* dst) {
        const half_t* slab = Wst + (size_t)ks * (NMAT * 64);
        #pragma unroll
        for (int i = 0; i < 3; ++i) {
            int f = t + 512 * i;                          // 0..1535 chunks
            gload_lds16(slab + (size_t)f * 8, dst + (size_t)f * 8);
        }
    };
    auto xload = [&](int ks, float4& xa, float4& xb) {
        const float* xp = xrow + ks * 32;
        xa = *(const float4*)xp;
        xb = *(const float4*)(xp + 4);
    };
    auto pcomp = [&](const half_t* Wb, const float4& xa, const float4& xb) {
        float xv[8] = {xa.x, xa.y, xa.z, xa.w, xb.x, xb.y, xb.z, xb.w};
        half8 ah, al;
        #pragma unroll
        for (int j = 0; j < 8; ++j) {
            half_t hi = (half_t)xv[j];
            ah[j] = hi;
            al[j] = (half_t)(xv[j] - (float)hi);
        }
        const half_t* rq = Wb + (size_t)nq * 64;
        const half_t* rk = rq + (size_t)64 * 64;
        const half_t* rv = rq + (size_t)128 * 64;
        half8 bhq = *(const half8*)(rq + oh);
        half8 blq = *(const half8*)(rq + ol);
        half8 bhk = *(const half8*)(rk + oh);
        half8 blk = *(const half8*)(rk + ol);
        half8 bhv = *(const half8*)(rv + oh);
        __builtin_amdgcn_s_setprio(1);
        aqh = __builtin_amdgcn_mfma_f32_16x16x32_f16(ah, bhq, aqh, 0, 0, 0);
        aqm = __builtin_amdgcn_mfma_f32_16x16x32_f16(al, bhq, aqm, 0, 0, 0);
        aqm = __builtin_amdgcn_mfma_f32_16x16x32_f16(ah, blq, aqm, 0, 0, 0);
        akh = __builtin_amdgcn_mfma_f32_16x16x32_f16(ah, bhk, akh, 0, 0, 0);
        akm = __builtin_amdgcn_mfma_f32_16x16x32_f16(al, bhk, akm, 0, 0, 0);
        akm = __builtin_amdgcn_mfma_f32_16x16x32_f16(ah, blk, akm, 0, 0, 0);
        av  = __builtin_amdgcn_mfma_f32_16x16x32_f16(ah, bhv, av,  0, 0, 0);
        __builtin_amdgcn_s_setprio(0);
    };

    float4 xa0, xb0, xa1, xb1;
    stage(0, W_s[0]);
    xload(0, xa0, xb0);

    for (int ks = 0; ks < 24; ks += 2) {
        // even step: compute ks from buf0; prefetch ks+1 into buf1
        stage(ks + 1, W_s[1]);
        xload(ks + 1, xa1, xb1);
        asm volatile("s_waitcnt vmcnt(5)" ::: "memory");
        __builtin_amdgcn_s_barrier();
        __builtin_amdgcn_sched_barrier(0);
        pcomp(W_s[0], xa0, xb0);
        asm volatile("s_waitcnt lgkmcnt(0)" ::: "memory");
        __builtin_amdgcn_s_barrier();

        // odd step: compute ks+1 from buf1; prefetch ks+2 into buf0
        if (ks + 2 < 24) {
            stage(ks + 2, W_s[0]);
            xload(ks + 2, xa0, xb0);
            asm volatile("s_waitcnt vmcnt(5)" ::: "memory");
        } else {
            asm volatile("s_waitcnt vmcnt(0)" ::: "memory");
        }
        __builtin_amdgcn_s_barrier();
        __builtin_amdgcn_sched_barrier(0);
        pcomp(W_s[1], xa1, xb1);
        asm volatile("s_waitcnt lgkmcnt(0)" ::: "memory");
        __builtin_amdgcn_s_barrier();
    }

    // Epilogue. C-layout (16x16): row = quad*4+r, col = lane&15.
    const int srow0 = blockIdx.x * 32 + msub * 16 + quad * 4;
    const int hcol = nsplit * 16 + col;
    #pragma unroll
    for (int r = 0; r < 4; ++r) {
        int srow = srow0 + r;
        float vq = (aqh[r] + aqm[r]) * 0.125f;   // fold 1/sqrt(H) into q
        half_t hq = (half_t)vq;
        qhi[(size_t)srow * H + hcol] = hq;
        qlo[(size_t)srow * H + hcol] = (half_t)(vq - (float)hq);
        float vk = akh[r] + akm[r];
        half_t hk = (half_t)vk;
        khi[(size_t)srow * H + hcol] = hk;
        klo[(size_t)srow * H + hcol] = (half_t)(vk - (float)hk);
    }
    {   // v transposed [b][dim][S]
        half4 pk;
        #pragma unroll
        for (int r = 0; r < 4; ++r) pk[r] = (half_t)av[r];
        int bb = srow0 >> 12, s0 = srow0 & (S - 1);
        *(half4*)(vt + ((size_t)(bb * H + hcol)) * S + s0) = pk;
    }
}

// ---------------- Flash attention v6: R2 structure + counted-vmcnt ----------------
// grid 256 x 512 thr. Block: 64 q-rows, 8 waves = 2 qsub(32 rows) x 4 ksw(32 keys).
// LDS 64 KB (dbuf x (Khi 16K | Klo 16K)). K staged via global_load_lds
// (pre-swizzled source, linear LDS dest); V frags direct from L2.
// NO __syncthreads in the loop (its vmcnt(0) drain exposed the full DMA
// latency each tile). Per tile:
//   [V loads][stage kt+1 -> buf^1][vmcnt(4)][s_barrier][QK+softmax+PV]
//   [lgkmcnt(0)][s_barrier]
// vmcnt(4) leaves only the newest 4 ops (stage kt+1) in flight; everything
// older (stage kt from the previous iteration) is forced complete before the
// barrier -- reorder-proof. Barrier B (no drain) guards buffer overwrite.
// Swapped QK^T keeps P in registers (cvt_pkrtz + permlane32_swap).
__global__ __launch_bounds__(512, 4) void flash_kernel(
    const half_t* __restrict__ qhi, const half_t* __restrict__ qlo,
    const half_t* __restrict__ khi, const half_t* __restrict__ klo,
    const half_t* __restrict__ vt, float* __restrict__ out)
{
    __shared__ __align__(16) char smem[66560];   // buf0 32K | buf1 32K; epi: Oc 64K + l_s 1K

    const int t = threadIdx.x;
    const int w = t >> 6, lane = t & 63;
    const int n32 = lane & 31, l5 = lane >> 5;
    const int ksw = w & 3, qsub = w >> 2;         // 4 key-slices x 2 q-subtiles

    // XCD-aware swizzle: XCD pair {2b,2b+1} serves batch b (K/V fit its L2s)
    const int bid = blockIdx.x;
    const int b = (bid & 7) >> 1;
    const int qt = ((bid >> 3) << 1) | (bid & 1); // 0..63
    const int qrow0 = b * S + qt * 64;

    const half_t* kh_g = khi + (size_t)b * S * H;
    const half_t* kl_g = klo + (size_t)b * S * H;
    const half_t* vt_g = vt + (size_t)b * H * S;

    // Q as MFMA B-fragment: n = q-row = lane&31, k = l5*8+j  (4 k-steps, hi/lo)
    half8 qh[4], ql[4];
    #pragma unroll
    for (int ks = 0; ks < 4; ++ks) {
        size_t off = (size_t)(qrow0 + qsub * 32 + n32) * H + ks * 16 + l5 * 8;
        qh[ks] = *(const half8*)(qhi + off);
        ql[ks] = *(const half8*)(qlo + off);
    }

    // stage one 128-key tile: Khi (16 KB) + Klo (16 KB), 4 x 16B per thread.
    // source pre-swizzled (chunk c at pos c^(key&7)) so LDS dest is linear.
    auto stage = [&](int kt, int buf) {
        char* base = smem + buf * 32768;
        #pragma unroll
        for (int i = 0; i < 4; ++i) {
            int f2 = ((i & 1) << 9) + t;          // chunk id within section, 0..1023
            int keyl = f2 >> 3;
            int c = (f2 & 7) ^ (keyl & 7);
            const half_t* g = (i < 2 ? kh_g : kl_g)
                            + ((size_t)(kt * 128 + keyl)) * H + c * 8;
            gload_lds16(g, base + (i < 2 ? 0 : 16384) + f2 * 16);
        }
    };

    stage(0, 0);

    f32x16 Oa, Ob;
    #pragma unroll
    for (int r = 0; r < 16; ++r) { Oa[r] = 0.f; Ob[r] = 0.f; }
    float lacc = 0.f;

    const int keyl = ksw * 32 + n32;              // this lane's key in the tile

    for (int kt = 0; kt < 32; ++kt) {
        const int cur = kt & 1;

        // V B-frags for the CURRENT tile, direct from global (L2/L1-resident).
        half8 vf00, vf10, vf01, vf11;
        {
            const half_t* vp = vt_g + (size_t)n32 * S + kt * 128 + ksw * 32 + l5 * 8;
            vf00 = *(const half8*)(vp);            // ks2=0, dims 0..31
            vf10 = *(const half8*)(vp + 16);       // ks2=1, dims 0..31
            vf01 = *(const half8*)(vp + 32 * S);   // ks2=0, dims 32..63
            vf11 = *(const half8*)(vp + 32 * S + 16);
        }

        if (kt < 31) stage(kt + 1, cur ^ 1);

        // counted wait: newest 4 (stage kt+1) stay in flight; stage kt and
        // the V loads are forced complete. Then barrier A: tile kt staged
        // by ALL waves and visible.
        asm volatile("s_waitcnt vmcnt(4)" ::: "memory");
        __builtin_amdgcn_s_barrier();
        __builtin_amdgcn_sched_barrier(0);

        half_t* khs = (half_t*)(smem + cur * 32768);
        half_t* kls = khs + 8192;

        // ---- QK^T swapped: acc = K*Q^T, lane n32 = q-row, regs = keys ----
        f32x16 acc, acc2;
        #pragma unroll
        for (int r = 0; r < 16; ++r) { acc[r] = 0.f; acc2[r] = 0.f; }
        __builtin_amdgcn_s_setprio(1);
        #pragma unroll
        for (int ks = 0; ks < 4; ++ks) {
            int phys = ((ks * 2 + l5) ^ (keyl & 7)) * 8;
            half8 bh = *(const half8*)(khs + keyl * 64 + phys);
            half8 bl = *(const half8*)(kls + keyl * 64 + phys);
            acc  = __builtin_amdgcn_mfma_f32_32x32x16_f16(bh, qh[ks], acc,  0, 0, 0);
            acc2 = __builtin_amdgcn_mfma_f32_32x32x16_f16(bh, ql[ks], acc2, 0, 0, 0);
            acc  = __builtin_amdgcn_mfma_f32_32x32x16_f16(bl, qh[ks], acc,  0, 0, 0);
        }
        __builtin_amdgcn_s_setprio(0);
        #pragma unroll
        for (int r = 0; r < 16; ++r) acc[r] += acc2[r];

        // ---- fixed-max softmax, P stays in registers ----
        // key(r) = (r&3) + 8*(r>>2) + 4*l5  (acc already = qk/8)
        unsigned int h0[4], h1[4];
        #pragma unroll
        for (int m = 0; m < 4; ++m) {
            float p0 = exp2f((floorf(acc[4 * m + 0]) - 8.0f) * LOG2E);
            float p1 = exp2f((floorf(acc[4 * m + 1]) - 8.0f) * LOG2E);
            float p2 = exp2f((floorf(acc[4 * m + 2]) - 8.0f) * LOG2E);
            float p3 = exp2f((floorf(acc[4 * m + 3]) - 8.0f) * LOG2E);
            lacc += p0 + p1 + p2 + p3;
            h0[m] = __builtin_bit_cast(unsigned int, __builtin_amdgcn_cvt_pkrtz(p0, p1));
            h1[m] = __builtin_bit_cast(unsigned int, __builtin_amdgcn_cvt_pkrtz(p2, p3));
        }

        // ---- PV: build A-frags with permlane32_swap, no LDS ----
        __builtin_amdgcn_s_setprio(1);
        #pragma unroll
        for (int ks2 = 0; ks2 < 2; ++ks2) {
            auto s1 = __builtin_amdgcn_permlane32_swap(h0[2 * ks2], h0[2 * ks2 + 1], false, false);
            auto s2 = __builtin_amdgcn_permlane32_swap(h1[2 * ks2], h1[2 * ks2 + 1], false, false);
            uint4v pw;
            pw[0] = s1[0]; pw[1] = s2[0]; pw[2] = s1[1]; pw[3] = s2[1];
            half8 pf = __builtin_bit_cast(half8, pw);
            Oa = __builtin_amdgcn_mfma_f32_32x32x16_f16(pf, ks2 ? vf10 : vf00, Oa, 0, 0, 0);
            Ob = __builtin_amdgcn_mfma_f32_32x32x16_f16(pf, ks2 ? vf11 : vf01, Ob, 0, 0, 0);
        }
        __builtin_amdgcn_s_setprio(0);

        // barrier B (no drain): everyone done reading buf[cur] before the
        // next iteration's stage(kt+2) overwrites it.
        asm volatile("s_waitcnt lgkmcnt(0)" ::: "memory");
        __builtin_amdgcn_s_barrier();
    }

    // ---- denominator: other 16 keys live in the opposite lane-half ----
    lacc += __shfl_xor(lacc, 32);

    // ---- combine the 4 key-slice partials via LDS ----
    // Oc [4 ksw][64 rows][64 dims] = 64 KB; l_s [4][64] after it.
    float* Oc  = (float*)smem;
    float* l_s = (float*)(smem + 65536);
    #pragma unroll
    for (int r = 0; r < 16; ++r) {
        int rowl = qsub * 32 + (r & 3) + 8 * (r >> 2) + 4 * l5;
        Oc[(ksw * 64 + rowl) * 64 + n32]      = Oa[r];
        Oc[(ksw * 64 + rowl) * 64 + 32 + n32] = Ob[r];
    }
    if (lane < 32) l_s[ksw * 64 + qsub * 32 + n32] = lacc;
    __syncthreads();

    {
        int row = t >> 3;            // 0..63
        int d0 = (t & 7) * 8;        // 0..56
        float den = l_s[row] + l_s[64 + row] + l_s[128 + row] + l_s[192 + row];
        float s0 = 0.f, s1 = 0.f, s2 = 0.f, s3 = 0.f;
        float s4 = 0.f, s5 = 0.f, s6 = 0.f, s7 = 0.f;
        #pragma unroll
        for (int k = 0; k < 4; ++k) {
            const float* oc = Oc + (size_t)(k * 64 + row) * 64 + d0;
            float4 a = *(const float4*)oc;
            float4 bq = *(const float4*)(oc + 4);
            s0 += a.x;  s1 += a.y;  s2 += a.z;  s3 += a.w;
            s4 += bq.x; s5 += bq.y; s6 += bq.z; s7 += bq.w;
        }
        float inv = 1.f / den;
        float4 o1 = make_float4(s0 * inv, s1 * inv, s2 * inv, s3 * inv);
        float4 o2 = make_float4(s4 * inv, s5 * inv, s6 * inv, s7 * inv);
        float* op = out + (size_t)(qrow0 + row) * H + d0;
        *(float4*)op = o1;
        *(float4*)(op + 4) = o2;
    }
}

extern "C" void kernel_launch(void* const* d_in, const int* in_sizes, int n_in,
                              void* d_out, int out_size, void* d_ws, size_t ws_size,
                              hipStream_t stream) {
    const float* x  = (const float*)d_in[0];
    const float* Wq = (const float*)d_in[1];
    const float* Wk = (const float*)d_in[2];
    const float* Wv = (const float*)d_in[3];
    float* outp = (float*)d_out;

    const size_t N = (size_t)B * S * H;          // 1,048,576
    half_t* qhi = (half_t*)d_ws;
    half_t* qlo = qhi + N;
    half_t* khi = qlo + N;
    half_t* klo = khi + N;
    half_t* vt  = klo + N;
    half_t* Wst = vt + N;                        // 294912 halves

    wprep_kernel<<<(3 * H * E) / 256, 256, 0, stream>>>(Wq, Wk, Wv, Wst);
    proj_kernel<<<(B * S) / 32, 512, 0, stream>>>(x, Wst, qhi, qlo, khi, klo, vt);
    flash_kernel<<<B * (S / 64), 512, 0, stream>>>(qhi, qlo, khi, klo, vt, outp);
}

// Round 6
// 171.800 us; speedup vs baseline: 1.4260x; 1.3003x over previous
//
#include <hip/hip_runtime.h>
#include <math.h>
#include <stdint.h>

#define B 4
#define S 4096
#define E 768
#define H 64
#define NMAT 192   // 3*64 output columns (q|k|v)

typedef _Float16 half_t;
typedef __attribute__((ext_vector_type(8))) _Float16 half8;
typedef __attribute__((ext_vector_type(4))) _Float16 half4;
typedef __attribute__((ext_vector_type(4))) float f32x4;
typedef __attribute__((ext_vector_type(16))) float f32x16;
typedef __attribute__((ext_vector_type(4))) unsigned int uint4v;

#define LOG2E 1.4426950408889634f

__device__ __forceinline__ void gload_lds16(const void* g, void* l) {
    __builtin_amdgcn_global_load_lds(
        (const __attribute__((address_space(1))) unsigned int*)g,
        (__attribute__((address_space(3))) unsigned int*)l, 16, 0, 0);
}

// ---------------- W prep: fp16 Dekker split, chunk-swizzled ----------------
// Wst layout: [kstep 24][n 192][8 chunks of 8 halves].
// Logical chunk j: 0..3 = hi[kk 0..31], 4..7 = lo[kk 0..31]; stored at
// physical chunk p = j ^ (n&7) so proj's linear global_load_lds image gives
// bank-spread fragment reads (same scheme as flash's K staging).
__global__ __launch_bounds__(256) void wprep_kernel(
    const float* __restrict__ Wq, const float* __restrict__ Wk,
    const float* __restrict__ Wv, half_t* __restrict__ Wst)
{
    int gid = blockIdx.x * 256 + threadIdx.x;     // 0..147455
    int m = gid / (H * E);
    int rem = gid - m * (H * E);
    int h = rem / E;
    int e = rem - h * E;
    const float* W = (m == 0) ? Wq : (m == 1) ? Wk : Wv;
    float val = W[h * E + e];
    half_t hi = (half_t)val;
    float lo = val - (float)hi;
    int n = m * H + h;
    int ks = e >> 5, kk = e & 31;
    int jh = kk >> 3, pos = kk & 7, sw = n & 7;
    size_t base = ((size_t)(ks * NMAT + n)) * 64;
    Wst[base + ((jh ^ sw) << 3) + pos]       = hi;
    Wst[base + (((jh + 4) ^ sw) << 3) + pos] = (half_t)lo;
}

// ---------------- Projection v4: DMA-staged, counted-vmcnt pipeline ----------------
// (unchanged from round 5 -- measured equal to the R2 version, ~51 us)
__global__ __launch_bounds__(512, 4) void proj_kernel(
    const float* __restrict__ x, const half_t* __restrict__ Wst,
    half_t* __restrict__ qhi, half_t* __restrict__ qlo,
    half_t* __restrict__ khi, half_t* __restrict__ klo,
    half_t* __restrict__ vt)
{
    __shared__ __align__(16) half_t W_s[2][NMAT * 64];   // 2 x 24576 B

    const int t = threadIdx.x;
    const int w = t >> 6, lane = t & 63;
    const int col = lane & 15, quad = lane >> 4;
    const int nsplit = w & 3, msub = w >> 2;
    const int mrow = blockIdx.x * 32 + msub * 16 + col;

    f32x4 aqh = {0.f,0.f,0.f,0.f}, aqm = {0.f,0.f,0.f,0.f};
    f32x4 akh = {0.f,0.f,0.f,0.f}, akm = {0.f,0.f,0.f,0.f};
    f32x4 av  = {0.f,0.f,0.f,0.f};

    const float* xrow = x + (size_t)mrow * E + quad * 8;
    const int nq = nsplit * 16 + col;                     // q row 0..63
    const int oh = (quad ^ (col & 7)) << 3;               // hi chunk offset
    const int ol = ((quad + 4) ^ (col & 7)) << 3;         // lo chunk offset

    auto stage = [&](int ks, half_t* dst) {
        const half_t* slab = Wst + (size_t)ks * (NMAT * 64);
        #pragma unroll
        for (int i = 0; i < 3; ++i) {
            int f = t + 512 * i;                          // 0..1535 chunks
            gload_lds16(slab + (size_t)f * 8, dst + (size_t)f * 8);
        }
    };
    auto xload = [&](int ks, float4& xa, float4& xb) {
        const float* xp = xrow + ks * 32;
        xa = *(const float4*)xp;
        xb = *(const float4*)(xp + 4);
    };
    auto pcomp = [&](const half_t* Wb, const float4& xa, const float4& xb) {
        float xv[8] = {xa.x, xa.y, xa.z, xa.w, xb.x, xb.y, xb.z, xb.w};
        half8 ah, al;
        #pragma unroll
        for (int j = 0; j < 8; ++j) {
            half_t hi = (half_t)xv[j];
            ah[j] = hi;
            al[j] = (half_t)(xv[j] - (float)hi);
        }
        const half_t* rq = Wb + (size_t)nq * 64;
        const half_t* rk = rq + (size_t)64 * 64;
        const half_t* rv = rq + (size_t)128 * 64;
        half8 bhq = *(const half8*)(rq + oh);
        half8 blq = *(const half8*)(rq + ol);
        half8 bhk = *(const half8*)(rk + oh);
        half8 blk = *(const half8*)(rk + ol);
        half8 bhv = *(const half8*)(rv + oh);
        __builtin_amdgcn_s_setprio(1);
        aqh = __builtin_amdgcn_mfma_f32_16x16x32_f16(ah, bhq, aqh, 0, 0, 0);
        aqm = __builtin_amdgcn_mfma_f32_16x16x32_f16(al, bhq, aqm, 0, 0, 0);
        aqm = __builtin_amdgcn_mfma_f32_16x16x32_f16(ah, blq, aqm, 0, 0, 0);
        akh = __builtin_amdgcn_mfma_f32_16x16x32_f16(ah, bhk, akh, 0, 0, 0);
        akm = __builtin_amdgcn_mfma_f32_16x16x32_f16(al, bhk, akm, 0, 0, 0);
        akm = __builtin_amdgcn_mfma_f32_16x16x32_f16(ah, blk, akm, 0, 0, 0);
        av  = __builtin_amdgcn_mfma_f32_16x16x32_f16(ah, bhv, av,  0, 0, 0);
        __builtin_amdgcn_s_setprio(0);
    };

    float4 xa0, xb0, xa1, xb1;
    stage(0, W_s[0]);
    xload(0, xa0, xb0);

    for (int ks = 0; ks < 24; ks += 2) {
        // even step: compute ks from buf0; prefetch ks+1 into buf1
        stage(ks + 1, W_s[1]);
        xload(ks + 1, xa1, xb1);
        asm volatile("s_waitcnt vmcnt(5)" ::: "memory");
        __builtin_amdgcn_s_barrier();
        __builtin_amdgcn_sched_barrier(0);
        pcomp(W_s[0], xa0, xb0);
        asm volatile("s_waitcnt lgkmcnt(0)" ::: "memory");
        __builtin_amdgcn_s_barrier();

        // odd step: compute ks+1 from buf1; prefetch ks+2 into buf0
        if (ks + 2 < 24) {
            stage(ks + 2, W_s[0]);
            xload(ks + 2, xa0, xb0);
            asm volatile("s_waitcnt vmcnt(5)" ::: "memory");
        } else {
            asm volatile("s_waitcnt vmcnt(0)" ::: "memory");
        }
        __builtin_amdgcn_s_barrier();
        __builtin_amdgcn_sched_barrier(0);
        pcomp(W_s[1], xa1, xb1);
        asm volatile("s_waitcnt lgkmcnt(0)" ::: "memory");
        __builtin_amdgcn_s_barrier();
    }

    // Epilogue. C-layout (16x16): row = quad*4+r, col = lane&15.
    const int srow0 = blockIdx.x * 32 + msub * 16 + quad * 4;
    const int hcol = nsplit * 16 + col;
    #pragma unroll
    for (int r = 0; r < 4; ++r) {
        int srow = srow0 + r;
        float vq = (aqh[r] + aqm[r]) * 0.125f;   // fold 1/sqrt(H) into q
        half_t hq = (half_t)vq;
        qhi[(size_t)srow * H + hcol] = hq;
        qlo[(size_t)srow * H + hcol] = (half_t)(vq - (float)hq);
        float vk = akh[r] + akm[r];
        half_t hk = (half_t)vk;
        khi[(size_t)srow * H + hcol] = hk;
        klo[(size_t)srow * H + hcol] = (half_t)(vk - (float)hk);
    }
    {   // v transposed [b][dim][S]
        half4 pk;
        #pragma unroll
        for (int r = 0; r < 4; ++r) pk[r] = (half_t)av[r];
        int bb = srow0 >> 12, s0 = srow0 & (S - 1);
        *(half4*)(vt + ((size_t)(bb * H + hcol)) * S + s0) = pk;
    }
}

// ---------------- Flash attention v7: R2 inner loop x 16 waves ----------------
// grid 256 x 1024 thr = 1 block/CU, 16 waves/CU = 4/SIMD (R2 ran at 2/SIMD:
// grid==CU-count means a second block per CU never existed -- the occupancy
// counter was flat ~20% across R0-R2).
// Block: 64 q-rows; two independent 8-wave HALVES split the 32 key-tiles by
// parity (half 0: even tiles, half 1: odd). Each half owns a private 64 KB
// double-buffered K region (identical geometry to R2). Inner loop, staging,
// softmax, PV are byte-for-byte R2 (single acc chain -- R5's second chain
// caused scratch spills). 8-way (2 half x 4 ksw) epilogue combine.
__global__ __launch_bounds__(1024, 4) void flash_kernel(
    const half_t* __restrict__ qhi, const half_t* __restrict__ qlo,
    const half_t* __restrict__ khi, const half_t* __restrict__ klo,
    const half_t* __restrict__ vt, float* __restrict__ out)
{
    // main loop: 2 halves x (dbuf x 32 KB) = 131072 B
    // epilogue:  Oc [8][64][64] f32 = 131072 B | l_s [8][64] f32 = 2048 B
    __shared__ __align__(16) char smem[133120];

    const int t = threadIdx.x;
    const int half = t >> 9;                      // key-parity group 0/1
    const int t9 = t & 511;
    const int w = t9 >> 6, lane = t & 63;
    const int n32 = lane & 31, l5 = lane >> 5;
    const int ksw = w & 3, qsub = w >> 2;         // 4 key-slices x 2 q-subtiles

    // XCD-aware swizzle: XCD pair {2b,2b+1} serves batch b (K/V fit its L2s)
    const int bid = blockIdx.x;
    const int b = (bid & 7) >> 1;
    const int qt = ((bid >> 3) << 1) | (bid & 1); // 0..63
    const int qrow0 = b * S + qt * 64;

    const half_t* kh_g = khi + (size_t)b * S * H;
    const half_t* kl_g = klo + (size_t)b * S * H;
    const half_t* vt_g = vt + (size_t)b * H * S;

    char* hbase = smem + half * 65536;            // this half's K region

    // Q as MFMA B-fragment: n = q-row = lane&31, k = l5*8+j  (4 k-steps, hi/lo)
    half8 qh[4], ql[4];
    #pragma unroll
    for (int ks = 0; ks < 4; ++ks) {
        size_t off = (size_t)(qrow0 + qsub * 32 + n32) * H + ks * 16 + l5 * 8;
        qh[ks] = *(const half8*)(qhi + off);
        ql[ks] = *(const half8*)(qlo + off);
    }

    // stage one 128-key tile for this half: Khi (16K) + Klo (16K), 4 x 16B/thread.
    // source pre-swizzled (chunk c at pos c^(key&7)) so LDS dest is linear.
    auto stage = [&](int kt, int buf) {
        char* base = hbase + buf * 32768;
        #pragma unroll
        for (int i = 0; i < 4; ++i) {
            int f2 = ((i & 1) << 9) + t9;         // chunk id within section, 0..1023
            int keyl = f2 >> 3;
            int c = (f2 & 7) ^ (keyl & 7);
            const half_t* g = (i < 2 ? kh_g : kl_g)
                            + ((size_t)(kt * 128 + keyl)) * H + c * 8;
            gload_lds16(g, base + (i < 2 ? 0 : 16384) + f2 * 16);
        }
    };

    stage(half, 0);

    f32x16 Oa, Ob;
    #pragma unroll
    for (int r = 0; r < 16; ++r) { Oa[r] = 0.f; Ob[r] = 0.f; }
    float lacc = 0.f;

    const int keyl = ksw * 32 + n32;              // this lane's key in the tile

    __syncthreads();   // close the iter-0 cross-wave staging race

    for (int i = 0; i < 16; ++i) {
        const int kt = 2 * i + half;              // this half's tile
        const int cur = i & 1;

        // V B-frags for the CURRENT tile, direct from global (L2/L1-resident).
        half8 vf00, vf10, vf01, vf11;
        {
            const half_t* vp = vt_g + (size_t)n32 * S + kt * 128 + ksw * 32 + l5 * 8;
            vf00 = *(const half8*)(vp);            // ks2=0, dims 0..31
            vf10 = *(const half8*)(vp + 16);       // ks2=1, dims 0..31
            vf01 = *(const half8*)(vp + 32 * S);   // ks2=0, dims 32..63
            vf11 = *(const half8*)(vp + 32 * S + 16);
        }

        if (i < 15) stage(kt + 2, cur ^ 1);

        half_t* khs = (half_t*)(hbase + cur * 32768);
        half_t* kls = khs + 8192;

        // ---- QK^T swapped: acc = K*Q^T, lane n32 = q-row, regs = keys ----
        f32x16 acc;
        #pragma unroll
        for (int r = 0; r < 16; ++r) acc[r] = 0.f;
        __builtin_amdgcn_s_setprio(1);
        #pragma unroll
        for (int ks = 0; ks < 4; ++ks) {
            int phys = ((ks * 2 + l5) ^ (keyl & 7)) * 8;
            half8 bh = *(const half8*)(khs + keyl * 64 + phys);
            half8 bl = *(const half8*)(kls + keyl * 64 + phys);
            acc = __builtin_amdgcn_mfma_f32_32x32x16_f16(bh, qh[ks], acc, 0, 0, 0);
            acc = __builtin_amdgcn_mfma_f32_32x32x16_f16(bh, ql[ks], acc, 0, 0, 0);
            acc = __builtin_amdgcn_mfma_f32_32x32x16_f16(bl, qh[ks], acc, 0, 0, 0);
        }
        __builtin_amdgcn_s_setprio(0);

        // ---- fixed-max softmax, P stays in registers ----
        // key(r) = (r&3) + 8*(r>>2) + 4*l5  (acc already = qk/8)
        unsigned int h0[4], h1[4];
        #pragma unroll
        for (int m = 0; m < 4; ++m) {
            float p0 = exp2f((floorf(acc[4 * m + 0]) - 8.0f) * LOG2E);
            float p1 = exp2f((floorf(acc[4 * m + 1]) - 8.0f) * LOG2E);
            float p2 = exp2f((floorf(acc[4 * m + 2]) - 8.0f) * LOG2E);
            float p3 = exp2f((floorf(acc[4 * m + 3]) - 8.0f) * LOG2E);
            lacc += p0 + p1 + p2 + p3;
            h0[m] = __builtin_bit_cast(unsigned int, __builtin_amdgcn_cvt_pkrtz(p0, p1));
            h1[m] = __builtin_bit_cast(unsigned int, __builtin_amdgcn_cvt_pkrtz(p2, p3));
        }

        // ---- PV: build A-frags with permlane32_swap, no LDS ----
        __builtin_amdgcn_s_setprio(1);
        #pragma unroll
        for (int ks2 = 0; ks2 < 2; ++ks2) {
            auto s1 = __builtin_amdgcn_permlane32_swap(h0[2 * ks2], h0[2 * ks2 + 1], false, false);
            auto s2 = __builtin_amdgcn_permlane32_swap(h1[2 * ks2], h1[2 * ks2 + 1], false, false);
            uint4v pw;
            pw[0] = s1[0]; pw[1] = s2[0]; pw[2] = s1[1]; pw[3] = s2[1];
            half8 pf = __builtin_bit_cast(half8, pw);
            Oa = __builtin_amdgcn_mfma_f32_32x32x16_f16(pf, ks2 ? vf10 : vf00, Oa, 0, 0, 0);
            Ob = __builtin_amdgcn_mfma_f32_32x32x16_f16(pf, ks2 ? vf11 : vf01, Ob, 0, 0, 0);
        }
        __builtin_amdgcn_s_setprio(0);

        __syncthreads();
    }

    // ---- denominator: other 16 keys live in the opposite lane-half ----
    lacc += __shfl_xor(lacc, 32);

    // ---- combine the 8 (half x ksw) partials via LDS ----
    float* Oc  = (float*)smem;                    // [8][64][64]
    float* l_s = (float*)(smem + 131072);         // [8][64]
    const int kslice = half * 4 + ksw;
    #pragma unroll
    for (int r = 0; r < 16; ++r) {
        int rowl = qsub * 32 + (r & 3) + 8 * (r >> 2) + 4 * l5;
        Oc[(kslice * 64 + rowl) * 64 + n32]      = Oa[r];
        Oc[(kslice * 64 + rowl) * 64 + 32 + n32] = Ob[r];
    }
    if (lane < 32) l_s[kslice * 64 + qsub * 32 + n32] = lacc;
    __syncthreads();

    {
        int row = t >> 4;            // 0..63
        int d0 = (t & 15) * 4;       // 0..60
        float den = 0.f;
        float s0 = 0.f, s1 = 0.f, s2 = 0.f, s3 = 0.f;
        #pragma unroll
        for (int k = 0; k < 8; ++k) {
            den += l_s[k * 64 + row];
            const float* oc = Oc + (size_t)(k * 64 + row) * 64 + d0;
            float4 a = *(const float4*)oc;
            s0 += a.x; s1 += a.y; s2 += a.z; s3 += a.w;
        }
        float inv = 1.f / den;
        float4 o1 = make_float4(s0 * inv, s1 * inv, s2 * inv, s3 * inv);
        float* op = out + (size_t)(qrow0 + row) * H + d0;
        *(float4*)op = o1;
    }
}

extern "C" void kernel_launch(void* const* d_in, const int* in_sizes, int n_in,
                              void* d_out, int out_size, void* d_ws, size_t ws_size,
                              hipStream_t stream) {
    const float* x  = (const float*)d_in[0];
    const float* Wq = (const float*)d_in[1];
    const float* Wk = (const float*)d_in[2];
    const float* Wv = (const float*)d_in[3];
    float* outp = (float*)d_out;

    const size_t N = (size_t)B * S * H;          // 1,048,576
    half_t* qhi = (half_t*)d_ws;
    half_t* qlo = qhi + N;
    half_t* khi = qlo + N;
    half_t* klo = khi + N;
    half_t* vt  = klo + N;
    half_t* Wst = vt + N;                        // 294912 halves

    wprep_kernel<<<(3 * H * E) / 256, 256, 0, stream>>>(Wq, Wk, Wv, Wst);
    proj_kernel<<<(B * S) / 32, 512, 0, stream>>>(x, Wst, qhi, qlo, khi, klo, vt);
    flash_kernel<<<B * (S / 64), 1024, 0, stream>>>(qhi, qlo, khi, klo, vt, outp);
}